// Round 8
// baseline (705.259 us; speedup 1.0000x reference)
//
#include <hip/hip_runtime.h>

#define INDIM 128
#define HID 256
#define NCLS 16
#define NGRAPH 64
#define CHUNK 8192

typedef __bf16 bf16_t;
typedef bf16_t bf16x8 __attribute__((ext_vector_type(8)));
typedef float f32x4 __attribute__((ext_vector_type(4)));

__device__ __forceinline__ float bfu_lo(unsigned v) {
    union { unsigned i; float f; } u; u.i = v << 16; return u.f;
}
__device__ __forceinline__ float bfu_hi(unsigned v) {
    union { unsigned i; float f; } u; u.i = v & 0xffff0000u; return u.f;
}
__device__ __forceinline__ unsigned short f2bf(float f) {  // RNE
    union { float f; unsigned i; } u; u.f = f;
    unsigned b = u.i;
    return (unsigned short)((b + 0x7fffu + ((b >> 16) & 1u)) >> 16);
}
__device__ __forceinline__ unsigned packbf(float lo, float hi) {
    return (unsigned)f2bf(lo) | ((unsigned)f2bf(hi) << 16);
}

// async 16B global->LDS
typedef __attribute__((address_space(1))) const unsigned gu32_t;
typedef __attribute__((address_space(3))) unsigned lu32_t;
__device__ __forceinline__ void gl_lds16(const void* g, void* l) {
    __builtin_amdgcn_global_load_lds((gu32_t*)g, (lu32_t*)l, 16, 0, 0);
}

#define ACC8(a, v)                                   \
    do {                                             \
        a[0] += bfu_lo((v).x); a[1] += bfu_hi((v).x); \
        a[2] += bfu_lo((v).y); a[3] += bfu_hi((v).y); \
        a[4] += bfu_lo((v).z); a[5] += bfu_hi((v).z); \
        a[6] += bfu_lo((v).w); a[7] += bfu_hi((v).w); \
    } while (0)

// ---------------- CSR build ----------------
__global__ void hist_kernel(const int* __restrict__ dst, int* __restrict__ deg, int E) {
    int e = blockIdx.x * blockDim.x + threadIdx.x;
    if (e < E) atomicAdd(&deg[dst[e]], 1);
}

__global__ void scan1_kernel(const int* __restrict__ deg, int* __restrict__ bsum, int n) {
    __shared__ int s[256];
    int t = threadIdx.x;
    int i = blockIdx.x * 256 + t;
    s[t] = (i < n) ? deg[i] : 0;
    __syncthreads();
    for (int off = 128; off > 0; off >>= 1) {
        if (t < off) s[t] += s[t + off];
        __syncthreads();
    }
    if (t == 0) bsum[blockIdx.x] = s[0];
}

__global__ void scan2_kernel(int* bsum, int nb) {
    __shared__ int s[1024];
    int t = threadIdx.x;
    int v = (t < nb) ? bsum[t] : 0;
    s[t] = v;
    __syncthreads();
    for (int off = 1; off < 1024; off <<= 1) {
        int u = (t >= off) ? s[t - off] : 0;
        __syncthreads();
        s[t] += u;
        __syncthreads();
    }
    if (t < nb) bsum[t] = s[t] - v;  // exclusive
}

__global__ void scan3_kernel(const int* __restrict__ deg, const int* __restrict__ bsum,
                             int* __restrict__ offs, int* __restrict__ gcur, int n) {
    __shared__ int s[256];
    int t = threadIdx.x;
    int i = blockIdx.x * 256 + t;
    int v = (i < n) ? deg[i] : 0;
    s[t] = v;
    __syncthreads();
    for (int off = 1; off < 256; off <<= 1) {
        int u = (t >= off) ? s[t - off] : 0;
        __syncthreads();
        s[t] += u;
        __syncthreads();
    }
    if (i < n) offs[i] = s[t] - v + bsum[blockIdx.x];
    if (t == 0) gcur[blockIdx.x] = bsum[blockIdx.x];
}

// ---------------- two-phase locality-aware edge sort ----------------
__global__ __launch_bounds__(256) void binA_kernel(const int* __restrict__ src,
                                                   const int* __restrict__ dst,
                                                   int* __restrict__ gcur,
                                                   unsigned* __restrict__ tmp,
                                                   int E, int nbuck) {
    __shared__ int hist[512];
    __shared__ int base[512];
    int t = threadIdx.x;
    int e0 = blockIdx.x * CHUNK;
    int e1 = min(e0 + CHUNK, E);
    for (int i = t; i < nbuck; i += 256) hist[i] = 0;
    __syncthreads();
    for (int e = e0 + t; e < e1; e += 256) atomicAdd(&hist[dst[e] >> 8], 1);
    __syncthreads();
    for (int i = t; i < nbuck; i += 256) {
        int c = hist[i];
        base[i] = (c > 0) ? atomicAdd(&gcur[i], c) : 0;
    }
    __syncthreads();
    for (int e = e0 + t; e < e1; e += 256) {
        int d = dst[e];
        int p = atomicAdd(&base[d >> 8], 1);
        tmp[p] = ((unsigned)(d & 255) << 17) | (unsigned)src[e];  // src < 2^17
    }
}

__global__ __launch_bounds__(256) void binB_kernel(const unsigned* __restrict__ tmp,
                                                   const int* __restrict__ offs,
                                                   int* __restrict__ srclist, int E, int n) {
    __shared__ int cur[256];
    int b = blockIdx.x;
    int node0 = b << 8;
    int nnodes = min(256, n - node0);
    int t = threadIdx.x;
    if (t < nnodes) cur[t] = offs[node0 + t];
    __syncthreads();
    int ebeg = offs[node0];
    int eend = (node0 + 256 < n) ? offs[node0 + 256] : E;
    for (int e = ebeg + t; e < eend; e += 256) {
        unsigned v = tmp[e];
        int p = atomicAdd(&cur[v >> 17], 1);
        srclist[p] = (int)(v & 0x1FFFFu);
    }
}

// ---------------- merged prep: cast x -> bf16, build Bt1/Bt2 ----------------
__global__ void prep_kernel(const float* __restrict__ x, unsigned short* __restrict__ xb,
                            const float* __restrict__ W1l, const float* __restrict__ W1r,
                            unsigned short* __restrict__ Bt1,
                            const float* __restrict__ W2l, const float* __restrict__ W2r,
                            unsigned short* __restrict__ Bt2, int castb) {
    int b = blockIdx.x, t = threadIdx.x;
    if (b < castb) {
        int i4 = (b * 256 + t) * 4;
        float4 v = *(const float4*)(x + i4);
        *(ushort4*)(xb + i4) = make_ushort4(f2bf(v.x), f2bf(v.y), f2bf(v.z), f2bf(v.w));
    } else if (b < castb + 256) {
        int idx = (b - castb) * 256 + t;
        int nn = idx >> 8, k = idx & 255;
        float v = (k < 128) ? W1l[(size_t)k * 256 + nn] : W1r[(size_t)(k - 128) * 256 + nn];
        Bt1[(size_t)nn * 256 + k] = f2bf(v);
    } else {
        int idx = (b - castb - 256) * 256 + t;
        int nn = idx >> 9, k = idx & 511;
        float v = (k < 256) ? W2l[(size_t)k * 256 + nn] : W2r[(size_t)(k - 256) * 256 + nn];
        Bt2[(size_t)nn * 512 + k] = f2bf(v);
    }
}

// ---------------- column-split mean aggregation ----------------
// One pass gathers a 64-col (128 B) slice of every neighbor row: per-pass working set
// 12.8 MB (vs 51 MB full rows) -> L3-resident; sequential passes keep the device-wide
// working set small. 8 lanes x 16 B = one slice; one load instruction serves 8 edges.
// STRIDE = row stride in bf16 elements (128 for x/mean1, 256 for h1/mean2).
template <int STRIDE>
__global__ void aggq_kernel(const unsigned short* __restrict__ tab,
                            const int* __restrict__ srclist,
                            const int* __restrict__ offs, const int* __restrict__ deg,
                            unsigned short* __restrict__ mean, int n, int col0) {
    int gid = blockIdx.x * blockDim.x + threadIdx.x;
    int node = gid >> 6, lane = gid & 63;
    if (node >= n) return;
    int g = lane >> 3, sub = lane & 7;   // 8 edge-groups x 8 lanes
    int st = __builtin_amdgcn_readfirstlane(offs[node]);
    int d = __builtin_amdgcn_readfirstlane(deg[node]);
    int end = st + d;
    float aA[8] = {0, 0, 0, 0, 0, 0, 0, 0}, aB[8] = {0, 0, 0, 0, 0, 0, 0, 0};
    const unsigned short* rb = tab + col0 + sub * 8;
    int e = st;
    for (; e + 15 < end; e += 16) {  // 2 loads -> 16 edges
        int s0 = srclist[e + g];
        int s1 = srclist[e + 8 + g];
        uint4 v0 = *(const uint4*)(rb + (size_t)s0 * STRIDE);
        uint4 v1 = *(const uint4*)(rb + (size_t)s1 * STRIDE);
        ACC8(aA, v0);
        ACC8(aB, v1);
    }
    for (; e + 7 < end; e += 8) {
        int s0 = srclist[e + g];
        uint4 v0 = *(const uint4*)(rb + (size_t)s0 * STRIDE);
        ACC8(aA, v0);
    }
    int rem = end - e;
    if (rem > 0) {  // 1..7 edges; groups with g >= rem contribute 0
        int s0 = srclist[e + ((g < rem) ? g : 0)];
        uint4 v0 = *(const uint4*)(rb + (size_t)s0 * STRIDE);
        if (g < rem) ACC8(aA, v0);
    }
    float inv = 1.f / fmaxf((float)d, 1.f);
    float tot[8];
#pragma unroll
    for (int i = 0; i < 8; ++i) {
        float s = aA[i] + aB[i];
        s += __shfl_xor(s, 8);
        s += __shfl_xor(s, 16);
        s += __shfl_xor(s, 32);
        tot[i] = s * inv;
    }
    if (lane < 8) {
        uint4 o;
        o.x = packbf(tot[0], tot[1]);
        o.y = packbf(tot[2], tot[3]);
        o.z = packbf(tot[4], tot[5]);
        o.w = packbf(tot[6], tot[7]);
        *(uint4*)(mean + (size_t)node * STRIDE + col0 + lane * 8) = o;
    }
}

// ======== MFMA GEMM with async A-staging (R6-proven) ========
template <int KH>  // per-half K: 128 (layer1) or 256 (layer2)
__global__ __launch_bounds__(256) void gemm_kernel(
        const bf16_t* __restrict__ A1, const bf16_t* __restrict__ A2,
        const bf16_t* __restrict__ Bt, const float* __restrict__ bias,
        unsigned short* __restrict__ H, int M) {
    constexpr int KT = 2 * KH;
    constexpr int NC = KT / 64;
    constexpr int CPH = KH / 64;
    __shared__ unsigned short As[64 * 64];  // 8 KB
    int t = threadIdx.x, wave = t >> 6, lane = t & 63;
    int quad = lane >> 4, l16 = lane & 15;
    int row0 = blockIdx.x * 64, n0 = wave * 64;

    f32x4 acc[4][4];
#pragma unroll
    for (int i = 0; i < 4; ++i)
#pragma unroll
        for (int j = 0; j < 4; ++j) acc[i][j] = (f32x4)(0.f);

    int rA = wave * 8 + (lane >> 3);
    int kb = lane & 7;
    int kswA = (kb ^ (rA & 7)) << 3;
    unsigned short* ldsA = &As[(size_t)(wave * 8) * 64];
    unsigned short* ldsB = &As[(size_t)(32 + wave * 8) * 64];

    const bf16_t* Bp = Bt + (size_t)(n0 + l16) * KT + quad * 8;

    for (int c = 0; c < NC; ++c) {
        const bf16_t* Ah = (c < CPH) ? A1 : A2;
        int kk = ((c < CPH) ? c : (c - CPH)) * 64;
        gl_lds16(Ah + (size_t)(row0 + rA) * KH + kk + kswA, ldsA);
        gl_lds16(Ah + (size_t)(row0 + 32 + rA) * KH + kk + kswA, ldsB);
        __syncthreads();
        int bk = c * 64;
#pragma unroll
        for (int sub = 0; sub < 2; ++sub) {
            bf16x8 af[4], bfr[4];
#pragma unroll
            for (int mi = 0; mi < 4; ++mi) {
                int r = mi * 16 + l16;
                int qb = sub * 4 + quad;
                af[mi] = *(const bf16x8*)&As[r * 64 + ((qb ^ (r & 7)) << 3)];
            }
#pragma unroll
            for (int ni = 0; ni < 4; ++ni)
                bfr[ni] = *(const bf16x8*)(Bp + (size_t)(ni * 16) * KT + bk + sub * 32);
#pragma unroll
            for (int mi = 0; mi < 4; ++mi)
#pragma unroll
                for (int ni = 0; ni < 4; ++ni)
                    acc[mi][ni] = __builtin_amdgcn_mfma_f32_16x16x32_bf16(
                        af[mi], bfr[ni], acc[mi][ni], 0, 0, 0);
        }
        __syncthreads();
    }

    float bv[4];
#pragma unroll
    for (int ni = 0; ni < 4; ++ni) bv[ni] = bias[n0 + ni * 16 + l16];
#pragma unroll
    for (int mi = 0; mi < 4; ++mi) {
#pragma unroll
        for (int r = 0; r < 4; ++r) {
            int row = row0 + mi * 16 + quad * 4 + r;
            if (row < M) {
#pragma unroll
                for (int ni = 0; ni < 4; ++ni) {
                    int col = n0 + ni * 16 + l16;
                    H[(size_t)row * 256 + col] = f2bf(fmaxf(acc[mi][ni][r] + bv[ni], 0.f));
                }
            }
        }
    }
}

// ---------------- segmented mean pool ----------------
__global__ void pool_kernel(const unsigned short* __restrict__ h2, const int* __restrict__ batch,
                            float* __restrict__ g, float* __restrict__ cnt, int n) {
    int col = threadIdx.x;
    int row0 = blockIdx.x * 256;
    float acc = 0.f;
    int cur = -1, seglen = 0;
    for (int r = 0; r < 256; ++r) {
        int row = row0 + r;
        if (row >= n) break;
        int b = batch[row];
        if (b != cur) {
            if (cur >= 0) {
                atomicAdd(&g[cur * 256 + col], acc);
                if (col == 0) atomicAdd(&cnt[cur], (float)seglen);
            }
            acc = 0.f; cur = b; seglen = 0;
        }
        union { unsigned i; float f; } u;
        u.i = ((unsigned)h2[(size_t)row * 256 + col]) << 16;
        acc += u.f;
        seglen++;
    }
    if (cur >= 0) {
        atomicAdd(&g[cur * 256 + col], acc);
        if (col == 0) atomicAdd(&cnt[cur], (float)seglen);
    }
}

// ---------------- classifier ----------------
__global__ void final_kernel(const float* __restrict__ g, const float* __restrict__ cnt,
                             const float* __restrict__ fcW, const float* __restrict__ fcb,
                             float* __restrict__ out) {
    int t = threadIdx.x;
    for (int o = t; o < NGRAPH * NCLS; o += 256) {
        int gi = o >> 4, c = o & 15;
        float inv = 1.f / fmaxf(cnt[gi], 1.f);
        float dot = 0.f;
        for (int k = 0; k < 256; ++k) dot += g[gi * 256 + k] * fcW[k * 16 + c];
        out[o] = dot * inv + fcb[c];
    }
}

extern "C" void kernel_launch(void* const* d_in, const int* in_sizes, int n_in, void* d_out,
                              int out_size, void* d_ws, size_t ws_size, hipStream_t stream) {
    const float* x   = (const float*)d_in[0];
    const int* edge  = (const int*)d_in[1];
    const int* batch = (const int*)d_in[2];
    const float* W1l = (const float*)d_in[3];
    const float* b1  = (const float*)d_in[4];
    const float* W1r = (const float*)d_in[5];
    const float* W2l = (const float*)d_in[6];
    const float* b2  = (const float*)d_in[7];
    const float* W2r = (const float*)d_in[8];
    const float* fcW = (const float*)d_in[9];
    const float* fcb = (const float*)d_in[10];
    float* out = (float*)d_out;

    const int n = in_sizes[0] / INDIM;   // 100000
    const int E = in_sizes[1] / 2;       // 1600000
    const int* src = edge;
    const int* dst = edge + E;
    const int nbuck = (n + 255) >> 8;    // 391

    char* ws = (char*)d_ws;
    size_t off = 0;
    auto alloc = [&](size_t bytes) {
        size_t p = off;
        off = (off + bytes + 511) & ~(size_t)511;
        return p;
    };
    size_t offs_o    = alloc((size_t)n * 4);
    size_t deg_o     = alloc((size_t)n * 4);          // zeroed
    size_t cnt_o     = alloc(64 * 4);                 // zeroed
    size_t g_o       = alloc(64 * 256 * 4);           // zeroed
    size_t zero_end  = off;
    size_t bsum_o    = alloc(1024 * 4);
    size_t gcur_o    = alloc(512 * 4);
    size_t srclist_o = alloc((size_t)E * 4);
    size_t bt1_o     = alloc(256 * 256 * 2);
    size_t bt2_o     = alloc(256 * 512 * 2);
    size_t xbm2_o    = alloc((size_t)n * 256 * 2);    // xb16 (n*128*2) -> mean2 (n*256*2)
    size_t mean1_o   = alloc((size_t)n * 128 * 2);
    size_t h1_o      = alloc((size_t)n * 256 * 2);
    size_t h2_o      = alloc((size_t)n * 256 * 2);    // tmp (CSR build) aliases here

    int*   offs    = (int*)(ws + offs_o);
    int*   deg     = (int*)(ws + deg_o);
    float* cnt     = (float*)(ws + cnt_o);
    float* g       = (float*)(ws + g_o);
    int*   bsum    = (int*)(ws + bsum_o);
    int*   gcur    = (int*)(ws + gcur_o);
    int*   srclist = (int*)(ws + srclist_o);
    unsigned short* Bt1   = (unsigned short*)(ws + bt1_o);
    unsigned short* Bt2   = (unsigned short*)(ws + bt2_o);
    unsigned short* xb16  = (unsigned short*)(ws + xbm2_o);  // dead after gemm1
    unsigned short* mean2 = (unsigned short*)(ws + xbm2_o);  // written by agg2 (after gemm1)
    unsigned short* mean1 = (unsigned short*)(ws + mean1_o);
    unsigned short* h1b   = (unsigned short*)(ws + h1_o);
    unsigned*       tmp   = (unsigned*)(ws + h2_o);          // dead before gemm2 writes h2
    unsigned short* h2b   = (unsigned short*)(ws + h2_o);

    hipMemsetAsync(ws + deg_o, 0, zero_end - deg_o, stream);

    int eb = (E + 255) / 256;
    int nb = (n + 255) / 256;  // 391
    hist_kernel<<<eb, 256, 0, stream>>>(dst, deg, E);
    scan1_kernel<<<nb, 256, 0, stream>>>(deg, bsum, n);
    scan2_kernel<<<1, 1024, 0, stream>>>(bsum, nb);
    scan3_kernel<<<nb, 256, 0, stream>>>(deg, bsum, offs, gcur, n);
    binA_kernel<<<(E + CHUNK - 1) / CHUNK, 256, 0, stream>>>(src, dst, gcur, tmp, E, nbuck);
    binB_kernel<<<nbuck, 256, 0, stream>>>(tmp, offs, srclist, E, n);

    int castb = n * INDIM / 4 / 256;  // 12500
    prep_kernel<<<castb + 256 + 512, 256, 0, stream>>>(x, xb16, W1l, W1r, Bt1, W2l, W2r, Bt2, castb);

    int aggb = (n * 64 + 255) / 256;
    int gemmb = (n + 63) / 64;  // 1563

    // layer 1: 2 column passes (128 B slices of 256 B rows)
    aggq_kernel<128><<<aggb, 256, 0, stream>>>(xb16, srclist, offs, deg, mean1, n, 0);
    aggq_kernel<128><<<aggb, 256, 0, stream>>>(xb16, srclist, offs, deg, mean1, n, 64);
    gemm_kernel<128><<<gemmb, 256, 0, stream>>>(
        (const bf16_t*)mean1, (const bf16_t*)xb16, (const bf16_t*)Bt1, b1, h1b, n);
    // layer 2: 4 column passes (128 B slices of 512 B rows)
    aggq_kernel<256><<<aggb, 256, 0, stream>>>(h1b, srclist, offs, deg, mean2, n, 0);
    aggq_kernel<256><<<aggb, 256, 0, stream>>>(h1b, srclist, offs, deg, mean2, n, 64);
    aggq_kernel<256><<<aggb, 256, 0, stream>>>(h1b, srclist, offs, deg, mean2, n, 128);
    aggq_kernel<256><<<aggb, 256, 0, stream>>>(h1b, srclist, offs, deg, mean2, n, 192);
    gemm_kernel<256><<<gemmb, 256, 0, stream>>>(
        (const bf16_t*)mean2, (const bf16_t*)h1b, (const bf16_t*)Bt2, b2, h2b, n);

    pool_kernel<<<nb, 256, 0, stream>>>(h2b, batch, g, cnt, n);
    final_kernel<<<1, 256, 0, stream>>>(g, cnt, fcW, fcb, out);
}

// Round 9
// 572.181 us; speedup vs baseline: 1.2326x; 1.2326x over previous
//
#include <hip/hip_runtime.h>

#define INDIM 128
#define HID 256
#define NCLS 16
#define NGRAPH 64
#define CHUNK 8192

typedef __bf16 bf16_t;
typedef bf16_t bf16x8 __attribute__((ext_vector_type(8)));
typedef float f32x4 __attribute__((ext_vector_type(4)));

__device__ __forceinline__ float bfu_lo(unsigned v) {
    union { unsigned i; float f; } u; u.i = v << 16; return u.f;
}
__device__ __forceinline__ float bfu_hi(unsigned v) {
    union { unsigned i; float f; } u; u.i = v & 0xffff0000u; return u.f;
}
__device__ __forceinline__ unsigned short f2bf(float f) {  // RNE
    union { float f; unsigned i; } u; u.f = f;
    unsigned b = u.i;
    return (unsigned short)((b + 0x7fffu + ((b >> 16) & 1u)) >> 16);
}
__device__ __forceinline__ unsigned packbf(float lo, float hi) {
    return (unsigned)f2bf(lo) | ((unsigned)f2bf(hi) << 16);
}

// async 16B global->LDS
typedef __attribute__((address_space(1))) const unsigned gu32_t;
typedef __attribute__((address_space(3))) unsigned lu32_t;
__device__ __forceinline__ void gl_lds16(const void* g, void* l) {
    __builtin_amdgcn_global_load_lds((gu32_t*)g, (lu32_t*)l, 16, 0, 0);
}

#define ACC8(a, v)                                   \
    do {                                             \
        a[0] += bfu_lo((v).x); a[1] += bfu_hi((v).x); \
        a[2] += bfu_lo((v).y); a[3] += bfu_hi((v).y); \
        a[4] += bfu_lo((v).z); a[5] += bfu_hi((v).z); \
        a[6] += bfu_lo((v).w); a[7] += bfu_hi((v).w); \
    } while (0)

// ---------------- CSR build ----------------
__global__ void hist_kernel(const int* __restrict__ dst, int* __restrict__ deg, int E) {
    int e = blockIdx.x * blockDim.x + threadIdx.x;
    if (e < E) atomicAdd(&deg[dst[e]], 1);
}

__global__ void scan1_kernel(const int* __restrict__ deg, int* __restrict__ bsum, int n) {
    __shared__ int s[256];
    int t = threadIdx.x;
    int i = blockIdx.x * 256 + t;
    s[t] = (i < n) ? deg[i] : 0;
    __syncthreads();
    for (int off = 128; off > 0; off >>= 1) {
        if (t < off) s[t] += s[t + off];
        __syncthreads();
    }
    if (t == 0) bsum[blockIdx.x] = s[0];
}

__global__ void scan2_kernel(int* bsum, int nb) {
    __shared__ int s[1024];
    int t = threadIdx.x;
    int v = (t < nb) ? bsum[t] : 0;
    s[t] = v;
    __syncthreads();
    for (int off = 1; off < 1024; off <<= 1) {
        int u = (t >= off) ? s[t - off] : 0;
        __syncthreads();
        s[t] += u;
        __syncthreads();
    }
    if (t < nb) bsum[t] = s[t] - v;  // exclusive
}

__global__ void scan3_kernel(const int* __restrict__ deg, const int* __restrict__ bsum,
                             int* __restrict__ offs, int* __restrict__ gcur, int n) {
    __shared__ int s[256];
    int t = threadIdx.x;
    int i = blockIdx.x * 256 + t;
    int v = (i < n) ? deg[i] : 0;
    s[t] = v;
    __syncthreads();
    for (int off = 1; off < 256; off <<= 1) {
        int u = (t >= off) ? s[t - off] : 0;
        __syncthreads();
        s[t] += u;
        __syncthreads();
    }
    if (i < n) offs[i] = s[t] - v + bsum[blockIdx.x];
    if (t == 0) gcur[blockIdx.x] = bsum[blockIdx.x];
}

// ---------------- two-phase locality-aware edge sort ----------------
__global__ __launch_bounds__(256) void binA_kernel(const int* __restrict__ src,
                                                   const int* __restrict__ dst,
                                                   int* __restrict__ gcur,
                                                   unsigned* __restrict__ tmp,
                                                   int E, int nbuck) {
    __shared__ int hist[512];
    __shared__ int base[512];
    int t = threadIdx.x;
    int e0 = blockIdx.x * CHUNK;
    int e1 = min(e0 + CHUNK, E);
    for (int i = t; i < nbuck; i += 256) hist[i] = 0;
    __syncthreads();
    for (int e = e0 + t; e < e1; e += 256) atomicAdd(&hist[dst[e] >> 8], 1);
    __syncthreads();
    for (int i = t; i < nbuck; i += 256) {
        int c = hist[i];
        base[i] = (c > 0) ? atomicAdd(&gcur[i], c) : 0;
    }
    __syncthreads();
    for (int e = e0 + t; e < e1; e += 256) {
        int d = dst[e];
        int p = atomicAdd(&base[d >> 8], 1);
        tmp[p] = ((unsigned)(d & 255) << 17) | (unsigned)src[e];  // src < 2^17
    }
}

__global__ __launch_bounds__(256) void binB_kernel(const unsigned* __restrict__ tmp,
                                                   const int* __restrict__ offs,
                                                   int* __restrict__ srclist, int E, int n) {
    __shared__ int cur[256];
    int b = blockIdx.x;
    int node0 = b << 8;
    int nnodes = min(256, n - node0);
    int t = threadIdx.x;
    if (t < nnodes) cur[t] = offs[node0 + t];
    __syncthreads();
    int ebeg = offs[node0];
    int eend = (node0 + 256 < n) ? offs[node0 + 256] : E;
    for (int e = ebeg + t; e < eend; e += 256) {
        unsigned v = tmp[e];
        int p = atomicAdd(&cur[v >> 17], 1);
        srclist[p] = (int)(v & 0x1FFFFu);
    }
}

// ---------------- merged prep: cast x -> bf16, build Bt1/Bt2 ----------------
__global__ void prep_kernel(const float* __restrict__ x, unsigned short* __restrict__ xb,
                            const float* __restrict__ W1l, const float* __restrict__ W1r,
                            unsigned short* __restrict__ Bt1,
                            const float* __restrict__ W2l, const float* __restrict__ W2r,
                            unsigned short* __restrict__ Bt2, int castb) {
    int b = blockIdx.x, t = threadIdx.x;
    if (b < castb) {
        int i4 = (b * 256 + t) * 4;
        float4 v = *(const float4*)(x + i4);
        *(ushort4*)(xb + i4) = make_ushort4(f2bf(v.x), f2bf(v.y), f2bf(v.z), f2bf(v.w));
    } else if (b < castb + 256) {
        int idx = (b - castb) * 256 + t;
        int nn = idx >> 8, k = idx & 255;
        float v = (k < 128) ? W1l[(size_t)k * 256 + nn] : W1r[(size_t)(k - 128) * 256 + nn];
        Bt1[(size_t)nn * 256 + k] = f2bf(v);
    } else {
        int idx = (b - castb - 256) * 256 + t;
        int nn = idx >> 9, k = idx & 511;
        float v = (k < 256) ? W2l[(size_t)k * 256 + nn] : W2r[(size_t)(k - 256) * 256 + nn];
        Bt2[(size_t)nn * 512 + k] = f2bf(v);
    }
}

// ---------------- mean aggregation (R7-proven single-pass wide-gather) ----------------
// agg1: quarter-wave per row (16 lanes x 16B = 256B row); one load instr = 4 edges.
__global__ void agg1_kernel(const unsigned short* __restrict__ xb, const int* __restrict__ srclist,
                            const int* __restrict__ offs, const int* __restrict__ deg,
                            unsigned short* __restrict__ mean, int n) {
    int gid = blockIdx.x * blockDim.x + threadIdx.x;
    int node = gid >> 6, lane = gid & 63;
    if (node >= n) return;
    int q = lane >> 4, sub = lane & 15;
    int st = __builtin_amdgcn_readfirstlane(offs[node]);
    int d = __builtin_amdgcn_readfirstlane(deg[node]);
    int end = st + d;
    float aA[8] = {0, 0, 0, 0, 0, 0, 0, 0}, aB[8] = {0, 0, 0, 0, 0, 0, 0, 0};
    const unsigned short* rb = xb + sub * 8;
    int e = st;
    for (; e + 7 < end; e += 8) {  // 2 loads -> 8 edges
        int s0 = srclist[e + q];
        int s1 = srclist[e + 4 + q];
        uint4 v0 = *(const uint4*)(rb + (size_t)s0 * 128);
        uint4 v1 = *(const uint4*)(rb + (size_t)s1 * 128);
        ACC8(aA, v0);
        ACC8(aB, v1);
    }
    for (; e + 3 < end; e += 4) {
        int s0 = srclist[e + q];
        uint4 v0 = *(const uint4*)(rb + (size_t)s0 * 128);
        ACC8(aA, v0);
    }
    int rem = end - e;
    if (rem > 0) {  // 1..3 edges; lanes with q >= rem contribute 0
        int s0 = srclist[e + ((q < rem) ? q : 0)];
        uint4 v0 = *(const uint4*)(rb + (size_t)s0 * 128);
        if (q < rem) ACC8(aA, v0);
    }
    float inv = 1.f / fmaxf((float)d, 1.f);
    float tot[8];
#pragma unroll
    for (int i = 0; i < 8; ++i) {
        float s = aA[i] + aB[i];
        s += __shfl_xor(s, 16);
        s += __shfl_xor(s, 32);
        tot[i] = s * inv;
    }
    if (lane < 16) {
        uint4 o;
        o.x = packbf(tot[0], tot[1]);
        o.y = packbf(tot[2], tot[3]);
        o.z = packbf(tot[4], tot[5]);
        o.w = packbf(tot[6], tot[7]);
        *(uint4*)(mean + (size_t)node * 128 + sub * 8) = o;
    }
}

// agg2: half-wave per row (32 lanes x 16B = 512B row); one load instr = 2 edges.
__global__ void agg2_kernel(const unsigned short* __restrict__ h1, const int* __restrict__ srclist,
                            const int* __restrict__ offs, const int* __restrict__ deg,
                            unsigned short* __restrict__ mean, int n) {
    int gid = blockIdx.x * blockDim.x + threadIdx.x;
    int node = gid >> 6, lane = gid & 63;
    if (node >= n) return;
    int half = lane >> 5, sub = lane & 31;
    int st = __builtin_amdgcn_readfirstlane(offs[node]);
    int d = __builtin_amdgcn_readfirstlane(deg[node]);
    int end = st + d;
    float aA[8] = {0, 0, 0, 0, 0, 0, 0, 0}, aB[8] = {0, 0, 0, 0, 0, 0, 0, 0};
    float aC[8] = {0, 0, 0, 0, 0, 0, 0, 0}, aD[8] = {0, 0, 0, 0, 0, 0, 0, 0};
    const unsigned short* rb = h1 + sub * 8;
    int e = st;
    for (; e + 7 < end; e += 8) {  // 4 loads -> 8 edges (4 KB in flight)
        int s0 = srclist[e + half];
        int s1 = srclist[e + 2 + half];
        int s2 = srclist[e + 4 + half];
        int s3 = srclist[e + 6 + half];
        uint4 v0 = *(const uint4*)(rb + (size_t)s0 * 256);
        uint4 v1 = *(const uint4*)(rb + (size_t)s1 * 256);
        uint4 v2 = *(const uint4*)(rb + (size_t)s2 * 256);
        uint4 v3 = *(const uint4*)(rb + (size_t)s3 * 256);
        ACC8(aA, v0);
        ACC8(aB, v1);
        ACC8(aC, v2);
        ACC8(aD, v3);
    }
    for (; e + 1 < end; e += 2) {
        int s0 = srclist[e + half];
        uint4 v0 = *(const uint4*)(rb + (size_t)s0 * 256);
        ACC8(aA, v0);
    }
    if (e < end) {  // 1 edge; half==1 contributes 0
        int s0 = srclist[e];
        uint4 v0 = *(const uint4*)(rb + (size_t)s0 * 256);
        if (half == 0) ACC8(aA, v0);
    }
    float inv = 1.f / fmaxf((float)d, 1.f);
    float tot[8];
#pragma unroll
    for (int i = 0; i < 8; ++i) {
        float s = (aA[i] + aB[i]) + (aC[i] + aD[i]);
        s += __shfl_xor(s, 32);
        tot[i] = s * inv;
    }
    if (half == 0) {
        uint4 o;
        o.x = packbf(tot[0], tot[1]);
        o.y = packbf(tot[2], tot[3]);
        o.z = packbf(tot[4], tot[5]);
        o.w = packbf(tot[6], tot[7]);
        *(uint4*)(mean + (size_t)node * 256 + sub * 8) = o;
    }
}

// ======== MFMA GEMM with async A-staging (R6-proven) ========
template <int KH>  // per-half K: 128 (layer1) or 256 (layer2)
__global__ __launch_bounds__(256) void gemm_kernel(
        const bf16_t* __restrict__ A1, const bf16_t* __restrict__ A2,
        const bf16_t* __restrict__ Bt, const float* __restrict__ bias,
        unsigned short* __restrict__ H, int M) {
    constexpr int KT = 2 * KH;
    constexpr int NC = KT / 64;
    constexpr int CPH = KH / 64;
    __shared__ unsigned short As[64 * 64];  // 8 KB
    int t = threadIdx.x, wave = t >> 6, lane = t & 63;
    int quad = lane >> 4, l16 = lane & 15;
    int row0 = blockIdx.x * 64, n0 = wave * 64;

    f32x4 acc[4][4];
#pragma unroll
    for (int i = 0; i < 4; ++i)
#pragma unroll
        for (int j = 0; j < 4; ++j) acc[i][j] = (f32x4)(0.f);

    int rA = wave * 8 + (lane >> 3);
    int kb = lane & 7;
    int kswA = (kb ^ (rA & 7)) << 3;
    unsigned short* ldsA = &As[(size_t)(wave * 8) * 64];
    unsigned short* ldsB = &As[(size_t)(32 + wave * 8) * 64];

    const bf16_t* Bp = Bt + (size_t)(n0 + l16) * KT + quad * 8;

    for (int c = 0; c < NC; ++c) {
        const bf16_t* Ah = (c < CPH) ? A1 : A2;
        int kk = ((c < CPH) ? c : (c - CPH)) * 64;
        gl_lds16(Ah + (size_t)(row0 + rA) * KH + kk + kswA, ldsA);
        gl_lds16(Ah + (size_t)(row0 + 32 + rA) * KH + kk + kswA, ldsB);
        __syncthreads();
        int bk = c * 64;
#pragma unroll
        for (int sub = 0; sub < 2; ++sub) {
            bf16x8 af[4], bfr[4];
#pragma unroll
            for (int mi = 0; mi < 4; ++mi) {
                int r = mi * 16 + l16;
                int qb = sub * 4 + quad;
                af[mi] = *(const bf16x8*)&As[r * 64 + ((qb ^ (r & 7)) << 3)];
            }
#pragma unroll
            for (int ni = 0; ni < 4; ++ni)
                bfr[ni] = *(const bf16x8*)(Bp + (size_t)(ni * 16) * KT + bk + sub * 32);
#pragma unroll
            for (int mi = 0; mi < 4; ++mi)
#pragma unroll
                for (int ni = 0; ni < 4; ++ni)
                    acc[mi][ni] = __builtin_amdgcn_mfma_f32_16x16x32_bf16(
                        af[mi], bfr[ni], acc[mi][ni], 0, 0, 0);
        }
        __syncthreads();
    }

    float bv[4];
#pragma unroll
    for (int ni = 0; ni < 4; ++ni) bv[ni] = bias[n0 + ni * 16 + l16];
#pragma unroll
    for (int mi = 0; mi < 4; ++mi) {
#pragma unroll
        for (int r = 0; r < 4; ++r) {
            int row = row0 + mi * 16 + quad * 4 + r;
            if (row < M) {
#pragma unroll
                for (int ni = 0; ni < 4; ++ni) {
                    int col = n0 + ni * 16 + l16;
                    H[(size_t)row * 256 + col] = f2bf(fmaxf(acc[mi][ni][r] + bv[ni], 0.f));
                }
            }
        }
    }
}

// ---------------- segmented mean pool: 64 rows/block, 4-row unroll ----------------
// (was 256 rows/block serial: 89 us at 294 GB/s, latency-starved. 1563 blocks ->
//  ~24 waves/CU, 4 independent loads in flight per thread.)
__global__ __launch_bounds__(256) void pool_kernel(const unsigned short* __restrict__ h2,
                                                   const int* __restrict__ batch,
                                                   float* __restrict__ g, float* __restrict__ cnt,
                                                   int n) {
    int col = threadIdx.x;
    int row0 = blockIdx.x * 64;
    int rend = min(row0 + 64, n);
    float acc = 0.f;
    int cur = -1, seglen = 0;
    int r = row0;
    for (; r + 3 < rend; r += 4) {
        int b0 = batch[r], b1 = batch[r + 1], b2 = batch[r + 2], b3 = batch[r + 3];
        unsigned short v0 = h2[(size_t)r * 256 + col];
        unsigned short v1 = h2[(size_t)(r + 1) * 256 + col];
        unsigned short v2 = h2[(size_t)(r + 2) * 256 + col];
        unsigned short v3 = h2[(size_t)(r + 3) * 256 + col];
        int bs[4] = {b0, b1, b2, b3};
        unsigned short vs[4] = {v0, v1, v2, v3};
#pragma unroll
        for (int j = 0; j < 4; ++j) {
            if (bs[j] != cur) {
                if (cur >= 0) {
                    atomicAdd(&g[cur * 256 + col], acc);
                    if (col == 0) atomicAdd(&cnt[cur], (float)seglen);
                }
                acc = 0.f; cur = bs[j]; seglen = 0;
            }
            union { unsigned i; float f; } u;
            u.i = ((unsigned)vs[j]) << 16;
            acc += u.f;
            seglen++;
        }
    }
    for (; r < rend; ++r) {
        int b = batch[r];
        if (b != cur) {
            if (cur >= 0) {
                atomicAdd(&g[cur * 256 + col], acc);
                if (col == 0) atomicAdd(&cnt[cur], (float)seglen);
            }
            acc = 0.f; cur = b; seglen = 0;
        }
        union { unsigned i; float f; } u;
        u.i = ((unsigned)h2[(size_t)r * 256 + col]) << 16;
        acc += u.f;
        seglen++;
    }
    if (cur >= 0) {
        atomicAdd(&g[cur * 256 + col], acc);
        if (col == 0) atomicAdd(&cnt[cur], (float)seglen);
    }
}

// ---------------- classifier ----------------
__global__ void final_kernel(const float* __restrict__ g, const float* __restrict__ cnt,
                             const float* __restrict__ fcW, const float* __restrict__ fcb,
                             float* __restrict__ out) {
    int t = threadIdx.x;
    for (int o = t; o < NGRAPH * NCLS; o += 256) {
        int gi = o >> 4, c = o & 15;
        float inv = 1.f / fmaxf(cnt[gi], 1.f);
        float dot = 0.f;
        for (int k = 0; k < 256; ++k) dot += g[gi * 256 + k] * fcW[k * 16 + c];
        out[o] = dot * inv + fcb[c];
    }
}

extern "C" void kernel_launch(void* const* d_in, const int* in_sizes, int n_in, void* d_out,
                              int out_size, void* d_ws, size_t ws_size, hipStream_t stream) {
    const float* x   = (const float*)d_in[0];
    const int* edge  = (const int*)d_in[1];
    const int* batch = (const int*)d_in[2];
    const float* W1l = (const float*)d_in[3];
    const float* b1  = (const float*)d_in[4];
    const float* W1r = (const float*)d_in[5];
    const float* W2l = (const float*)d_in[6];
    const float* b2  = (const float*)d_in[7];
    const float* W2r = (const float*)d_in[8];
    const float* fcW = (const float*)d_in[9];
    const float* fcb = (const float*)d_in[10];
    float* out = (float*)d_out;

    const int n = in_sizes[0] / INDIM;   // 100000
    const int E = in_sizes[1] / 2;       // 1600000
    const int* src = edge;
    const int* dst = edge + E;
    const int nbuck = (n + 255) >> 8;    // 391

    char* ws = (char*)d_ws;
    size_t off = 0;
    auto alloc = [&](size_t bytes) {
        size_t p = off;
        off = (off + bytes + 511) & ~(size_t)511;
        return p;
    };
    size_t offs_o    = alloc((size_t)n * 4);
    size_t deg_o     = alloc((size_t)n * 4);          // zeroed
    size_t cnt_o     = alloc(64 * 4);                 // zeroed
    size_t g_o       = alloc(64 * 256 * 4);           // zeroed
    size_t zero_end  = off;
    size_t bsum_o    = alloc(1024 * 4);
    size_t gcur_o    = alloc(512 * 4);
    size_t srclist_o = alloc((size_t)E * 4);
    size_t bt1_o     = alloc(256 * 256 * 2);
    size_t bt2_o     = alloc(256 * 512 * 2);
    size_t xbm2_o    = alloc((size_t)n * 256 * 2);    // xb16 (n*128*2) -> mean2 (n*256*2)
    size_t mean1_o   = alloc((size_t)n * 128 * 2);
    size_t h1_o      = alloc((size_t)n * 256 * 2);
    size_t h2_o      = alloc((size_t)n * 256 * 2);    // tmp (CSR build) aliases here

    int*   offs    = (int*)(ws + offs_o);
    int*   deg     = (int*)(ws + deg_o);
    float* cnt     = (float*)(ws + cnt_o);
    float* g       = (float*)(ws + g_o);
    int*   bsum    = (int*)(ws + bsum_o);
    int*   gcur    = (int*)(ws + gcur_o);
    int*   srclist = (int*)(ws + srclist_o);
    unsigned short* Bt1   = (unsigned short*)(ws + bt1_o);
    unsigned short* Bt2   = (unsigned short*)(ws + bt2_o);
    unsigned short* xb16  = (unsigned short*)(ws + xbm2_o);  // dead after gemm1
    unsigned short* mean2 = (unsigned short*)(ws + xbm2_o);  // written by agg2 (after gemm1)
    unsigned short* mean1 = (unsigned short*)(ws + mean1_o);
    unsigned short* h1b   = (unsigned short*)(ws + h1_o);
    unsigned*       tmp   = (unsigned*)(ws + h2_o);          // dead before gemm2 writes h2
    unsigned short* h2b   = (unsigned short*)(ws + h2_o);

    hipMemsetAsync(ws + deg_o, 0, zero_end - deg_o, stream);

    int eb = (E + 255) / 256;
    int nb = (n + 255) / 256;  // 391
    hist_kernel<<<eb, 256, 0, stream>>>(dst, deg, E);
    scan1_kernel<<<nb, 256, 0, stream>>>(deg, bsum, n);
    scan2_kernel<<<1, 1024, 0, stream>>>(bsum, nb);
    scan3_kernel<<<nb, 256, 0, stream>>>(deg, bsum, offs, gcur, n);
    binA_kernel<<<(E + CHUNK - 1) / CHUNK, 256, 0, stream>>>(src, dst, gcur, tmp, E, nbuck);
    binB_kernel<<<nbuck, 256, 0, stream>>>(tmp, offs, srclist, E, n);

    int castb = n * INDIM / 4 / 256;  // 12500
    prep_kernel<<<castb + 256 + 512, 256, 0, stream>>>(x, xb16, W1l, W1r, Bt1, W2l, W2r, Bt2, castb);

    int aggb = (n * 64 + 255) / 256;
    int gemmb = (n + 63) / 64;  // 1563

    agg1_kernel<<<aggb, 256, 0, stream>>>(xb16, srclist, offs, deg, mean1, n);
    gemm_kernel<128><<<gemmb, 256, 0, stream>>>(
        (const bf16_t*)mean1, (const bf16_t*)xb16, (const bf16_t*)Bt1, b1, h1b, n);
    agg2_kernel<<<aggb, 256, 0, stream>>>(h1b, srclist, offs, deg, mean2, n);
    gemm_kernel<256><<<gemmb, 256, 0, stream>>>(
        (const bf16_t*)mean2, (const bf16_t*)h1b, (const bf16_t*)Bt2, b2, h2b, n);

    pool_kernel<<<(n + 63) / 64, 256, 0, stream>>>(h2b, batch, g, cnt, n);
    final_kernel<<<1, 256, 0, stream>>>(g, cnt, fcW, fcb, out);
}